// Round 1
// baseline (138.523 us; speedup 1.0000x reference)
//
#include <hip/hip_runtime.h>

// IWD projection: out[b,n,c] = sum_k x[b, nn_idx[n,k], c] * w[n,k]
// w[n,k] = (1/(dist+eps)) / sum_k(1/(dist+eps))
// B=4, N_in=49152, C=64, N_out=196608, K=4. All f32.

#define IWD_EPS 1e-8f

__global__ __launch_bounds__(256) void IWD_ProjLayer_65876208386401_kernel(
    const float* __restrict__ x,       // (B, N_in, C)
    const int*   __restrict__ nn_idx,  // (N_out, K)
    const float* __restrict__ nn_dist, // (N_out, K)
    float* __restrict__ out)           // (B, N_out, C)
{
    constexpr int B = 4;
    constexpr int N_in = 49152;
    constexpr int C = 64;
    constexpr int N_out = 196608;

    const int tid = blockIdx.x * blockDim.x + threadIdx.x;
    const int n  = tid >> 4;        // 16 threads per output row
    const int cq = (tid & 15) * 4;  // starting channel (float4 per lane)
    if (n >= N_out) return;

    // Weights (same for all 16 lanes of this row — broadcast loads)
    const float4 d4 = *reinterpret_cast<const float4*>(nn_dist + (size_t)n * 4);
    const float i0 = 1.0f / (d4.x + IWD_EPS);
    const float i1 = 1.0f / (d4.y + IWD_EPS);
    const float i2 = 1.0f / (d4.z + IWD_EPS);
    const float i3 = 1.0f / (d4.w + IWD_EPS);
    const float r  = 1.0f / (i0 + i1 + i2 + i3);
    const float w0 = i0 * r, w1 = i1 * r, w2 = i2 * r, w3 = i3 * r;

    const int4 id = *reinterpret_cast<const int4*>(nn_idx + (size_t)n * 4);

    // Base offsets for the 4 gathered rows (channel dim contiguous)
    const size_t g0 = (size_t)id.x * C + cq;
    const size_t g1 = (size_t)id.y * C + cq;
    const size_t g2 = (size_t)id.z * C + cq;
    const size_t g3 = (size_t)id.w * C + cq;

#pragma unroll
    for (int b = 0; b < B; ++b) {
        const float* xb = x + (size_t)b * N_in * C;
        const float4 a0 = *reinterpret_cast<const float4*>(xb + g0);
        const float4 a1 = *reinterpret_cast<const float4*>(xb + g1);
        const float4 a2 = *reinterpret_cast<const float4*>(xb + g2);
        const float4 a3 = *reinterpret_cast<const float4*>(xb + g3);

        float4 o;
        o.x = a0.x * w0 + a1.x * w1 + a2.x * w2 + a3.x * w3;
        o.y = a0.y * w0 + a1.y * w1 + a2.y * w2 + a3.y * w3;
        o.z = a0.z * w0 + a1.z * w1 + a2.z * w2 + a3.z * w3;
        o.w = a0.w * w0 + a1.w * w1 + a2.w * w2 + a3.w * w3;

        *reinterpret_cast<float4*>(out + ((size_t)b * N_out + n) * C + cq) = o;
    }
}

extern "C" void kernel_launch(void* const* d_in, const int* in_sizes, int n_in,
                              void* d_out, int out_size, void* d_ws, size_t ws_size,
                              hipStream_t stream) {
    const float* x       = (const float*)d_in[0];
    const int*   nn_idx  = (const int*)d_in[1];
    const float* nn_dist = (const float*)d_in[2];
    float*       out     = (float*)d_out;

    constexpr int N_out = 196608;
    const int total_threads = N_out * 16;     // 16 lanes per row
    const int block = 256;
    const int grid = (total_threads + block - 1) / block;  // 12288

    IWD_ProjLayer_65876208386401_kernel<<<grid, block, 0, stream>>>(x, nn_idx, nn_dist, out);
}